// Round 8
// baseline (285.115 us; speedup 1.0000x reference)
//
#include <hip/hip_runtime.h>
#include <hip/hip_bf16.h>

typedef __attribute__((ext_vector_type(4))) float f32x4;
typedef __attribute__((ext_vector_type(8))) short bf16x8;

#define DINF 1e30f

// ---------------------------------------------------------------------------
// round-to-nearest-even fp32 -> bf16 bits (inputs are finite gaussians)
__device__ __forceinline__ unsigned short f2bf(float f) {
    unsigned int u = __builtin_bit_cast(unsigned int, f);
    u += 0x7FFFu + ((u >> 16) & 1u);
    return (unsigned short)(u >> 16);
}

// ---------------------------------------------------------------------------
// Kernel 1: L2-normalize each 768-dim row, emit bf16.
__global__ __launch_bounds__(256) void norm_bf16_kernel(
    const float* __restrict__ s1, const float* __restrict__ s2,
    __hip_bfloat16* __restrict__ o1, __hip_bfloat16* __restrict__ o2) {
    const int gb = blockIdx.x;
    const float* in;
    __hip_bfloat16* out;
    int rowbase;
    if (gb < 4096) { in = s1; out = o1; rowbase = gb * 4; }
    else           { in = s2; out = o2; rowbase = (gb - 4096) * 4; }
    const int wv = threadIdx.x >> 6;
    const int l  = threadIdx.x & 63;
    const int row = rowbase + wv;

    const float* rp = in + (size_t)row * 768 + l * 4;
    float4 x0 = *(const float4*)(rp);
    float4 x1 = *(const float4*)(rp + 256);
    float4 x2 = *(const float4*)(rp + 512);

    float s = x0.x*x0.x + x0.y*x0.y + x0.z*x0.z + x0.w*x0.w
            + x1.x*x1.x + x1.y*x1.y + x1.z*x1.z + x1.w*x1.w
            + x2.x*x2.x + x2.y*x2.y + x2.z*x2.z + x2.w*x2.w;
#pragma unroll
    for (int off = 32; off > 0; off >>= 1) s += __shfl_xor(s, off, 64);

    const float inv = 1.0f / fmaxf(sqrtf(s), 1e-12f);

    __hip_bfloat16* op = out + (size_t)row * 768 + l * 4;
    ushort4 o;
    o.x = f2bf(x0.x*inv); o.y = f2bf(x0.y*inv); o.z = f2bf(x0.z*inv); o.w = f2bf(x0.w*inv);
    *(ushort4*)(op) = o;
    o.x = f2bf(x1.x*inv); o.y = f2bf(x1.y*inv); o.z = f2bf(x1.z*inv); o.w = f2bf(x1.w*inv);
    *(ushort4*)(op + 256) = o;
    o.x = f2bf(x2.x*inv); o.y = f2bf(x2.y*inv); o.z = f2bf(x2.z*inv); o.w = f2bf(x2.w*inv);
    *(ushort4*)(op + 512) = o;
}

// ---------------------------------------------------------------------------
// Kernel 2: GEMM -> SKEWED bf16 distance matrix for the 2-wave DP.
// skew[b][row + 2*(col>>3) + 16*(col>>9)][col] = bf16(1 - dot(A[row],B[col]))
// Rows 0..1293, padded to 1296.
#define GLOAD_LDS16(g, l)                                                      \
    __builtin_amdgcn_global_load_lds(                                          \
        (const __attribute__((address_space(1))) void*)(g),                    \
        (__attribute__((address_space(3))) void*)(l), 16, 0, 0)

__global__ __launch_bounds__(256) void gemm_dist_kernel(
    const __hip_bfloat16* __restrict__ A, const __hip_bfloat16* __restrict__ B,
    __hip_bfloat16* __restrict__ skew) {
    __shared__ __hip_bfloat16 lA[128 * 64];  // [row][k], rows of 128B
    __shared__ __hip_bfloat16 lB[128 * 64];

    const int blk  = (blockIdx.x & 7) * 128 + (blockIdx.x >> 3);
    const int b    = blk >> 6;
    const int tile = blk & 63;
    const int tm = tile >> 3, tn = tile & 7;
    const int tid  = threadIdx.x;
    const int lane = tid & 63, w = tid >> 6;
    const int lr = lane & 15, lg = lane >> 4;
    const int wm = w >> 1, wn = w & 1;

    const __hip_bfloat16* Ab = A + (size_t)b * (1024 * 768) + (size_t)(tm * 128) * 768;
    const __hip_bfloat16* Bb = B + (size_t)b * (1024 * 768) + (size_t)(tn * 128) * 768;

    const int srow = tid >> 3;        // 0..31 (row within 32-row chunk)
    const int scol = (tid & 7) * 8;   // k-octet (8 bf16 = 16B per lane)

    char* lAb = (char*)lA;
    char* lBb = (char*)lB;

    f32x4 acc[4][4];
#pragma unroll
    for (int m = 0; m < 4; ++m)
#pragma unroll
        for (int n = 0; n < 4; ++n) acc[m][n] = (f32x4){0.f, 0.f, 0.f, 0.f};

    for (int k0 = 0; k0 < 768; k0 += 64) {
#pragma unroll
        for (int q = 0; q < 4; ++q) {
            GLOAD_LDS16(Ab + (size_t)(q * 32 + srow) * 768 + k0 + scol,
                        lAb + q * 4096 + w * 1024);
            GLOAD_LDS16(Bb + (size_t)(q * 32 + srow) * 768 + k0 + scol,
                        lBb + q * 4096 + w * 1024);
        }
        __syncthreads();

#pragma unroll
        for (int ks = 0; ks < 64; ks += 32) {
            bf16x8 af[4], bfr[4];
#pragma unroll
            for (int m = 0; m < 4; ++m)
                af[m] = *(const bf16x8*)&lA[(wm * 64 + m * 16 + lr) * 64 + ks + lg * 8];
#pragma unroll
            for (int n = 0; n < 4; ++n)
                bfr[n] = *(const bf16x8*)&lB[(wn * 64 + n * 16 + lr) * 64 + ks + lg * 8];
#pragma unroll
            for (int m = 0; m < 4; ++m)
#pragma unroll
                for (int n = 0; n < 4; ++n)
                    acc[m][n] = __builtin_amdgcn_mfma_f32_16x16x32_bf16(af[m], bfr[n], acc[m][n], 0, 0, 0);
        }
        __syncthreads();
    }

    unsigned short* S = (unsigned short*)skew + (size_t)b * (1296 * 1024);
#pragma unroll
    for (int m = 0; m < 4; ++m)
#pragma unroll
        for (int n = 0; n < 4; ++n) {
            const int cb = tn * 128 + wn * 64 + n * 16;         // col base (mult of 16)
            const int sbase = ((cb >> 3) << 1) + ((cb >> 9) << 4);
            const int soff  = sbase + ((lr >> 3) << 1);         // + 2*(lr/8)
#pragma unroll
            for (int r = 0; r < 4; ++r) {
                const int row = tm * 128 + wm * 64 + m * 16 + lg * 4 + r;
                S[(size_t)(row + soff) * 1024 + cb + lr] = f2bf(1.0f - acc[m][n][r]);
            }
        }
}

// ---------------------------------------------------------------------------
// Kernel 3: DTW DP, TWO waves per batch (128 lanes x 8 cols each).
// Global lane L = 64w + t owns cols [8L, 8L+8); step k -> row r = k - 2L - 16w.
// Intra-wave boundary: skew-2 shfl pipeline (a1/a2/a3), as proven r5-r7.
// Cross-wave boundary: wave0 lane63 publishes c7 (=dtw[k-126][511]) into a
// 32-slot LDS ring each step; wave1 lane0 consumes slot k-18 (left) / k-19
// (diag) via a 2-register pipeline fed by a read of slot k-14 each step.
// All slot distances within a superbody are in [6,23] mod 32 -> write/read
// sets disjoint; cross-superbody ordering via raw s_barrier + lgkmcnt(0)
// ONLY (no vmcnt drain -> DMA prefetch stays in flight across the barrier).
// DMA: per-wave private 3-bank x 8-row ring (1KB half-row per DMA, 8 per
// superbody, VWAIT(8)); bank rotation + 2-deep X/Y lookahead = r7 skeleton.

#define VWAIT(n) asm volatile("s_waitcnt vmcnt(" #n ")" ::: "memory")
#define SBAR()   asm volatile("s_waitcnt lgkmcnt(0)\n\ts_barrier" ::: "memory")

#define GLDMA16(g, l)                                                          \
    __builtin_amdgcn_global_load_lds(                                          \
        (const __attribute__((address_space(1))) void*)(g),                    \
        (__attribute__((address_space(3))) void*)(l), 16, 0, 0)

// skew row RW: this wave's 1KB half; lane t's 16B at Sb (+t*16 folded in).
#define LOADR(BK, SL, RW) GLDMA16(Sb + ((size_t)(RW) << 11), &ring[w][BK][SL][0])

#define ISSUE8(BK, BASE) do {                                                  \
    LOADR(BK, 0, (BASE));     LOADR(BK, 1, (BASE) + 1);                        \
    LOADR(BK, 2, (BASE) + 2); LOADR(BK, 3, (BASE) + 3);                        \
    LOADR(BK, 4, (BASE) + 4); LOADR(BK, 5, (BASE) + 5);                        \
    LOADR(BK, 6, (BASE) + 6); LOADR(BK, 7, (BASE) + 7);                        \
} while (0)

#define DSRD(BK, SL, N) do { N = ring[w][BK][SL][t]; } while (0)

// One DP step on 8 columns held in float4 P (8 bf16).
#define STEPCORE(P, E0EXPR) do {                                               \
    float bf_ = bndp[ro];                        /* bnd slot m-14 (wave0's) */ \
    unsigned u0_ = __builtin_bit_cast(unsigned, P.x);                          \
    unsigned u1_ = __builtin_bit_cast(unsigned, P.y);                          \
    unsigned u2_ = __builtin_bit_cast(unsigned, P.z);                          \
    unsigned u3_ = __builtin_bit_cast(unsigned, P.w);                          \
    float d0_ = __builtin_bit_cast(float, u0_ << 16);                          \
    float d1_ = __builtin_bit_cast(float, u0_ & 0xffff0000u);                  \
    float d2_ = __builtin_bit_cast(float, u1_ << 16);                          \
    float d3_ = __builtin_bit_cast(float, u1_ & 0xffff0000u);                  \
    float d4_ = __builtin_bit_cast(float, u2_ << 16);                          \
    float d5_ = __builtin_bit_cast(float, u2_ & 0xffff0000u);                  \
    float d6_ = __builtin_bit_cast(float, u3_ << 16);                          \
    float d7_ = __builtin_bit_cast(float, u3_ & 0xffff0000u);                  \
    float e0_ = (E0EXPR);                                                      \
    float c0_ = d0_ + e0_;                                                     \
    float c1_ = d1_ + fminf(fminf(p1, p0), c0_);                               \
    float c2_ = d2_ + fminf(fminf(p2, p1), c1_);                               \
    float c3_ = d3_ + fminf(fminf(p3, p2), c2_);                               \
    float c4_ = d4_ + fminf(fminf(p4, p3), c3_);                               \
    float c5_ = d5_ + fminf(fminf(p5, p4), c4_);                               \
    float c6_ = d6_ + fminf(fminf(p6, p5), c5_);                               \
    float c7_ = d7_ + fminf(fminf(p7, p6), c6_);                               \
    bndp[wo] = c7_;                 /* wave0 -> real ring; wave1 -> dead half */\
    p0=c0_; p1=c1_; p2=c2_; p3=c3_; p4=c4_; p5=c5_; p6=c6_; p7=c7_;            \
    a3 = a2; a2 = a1;                                                          \
    a1 = __shfl_up(c7_, 1, 64);                                                \
    float bv_ = isw1 ? b2 : DINF;   /* b2 = bnd slot m-16 */                   \
    a1 = lane0 ? bv_ : a1;                                                     \
    b2 = b1; b1 = bf_;                                                         \
    ro = (ro + 64) & 2047;                                                     \
    wo = wbase | ((wo + 64) & 2047);                                           \
} while (0)

#define STEPB(P)       STEPCORE(P, fminf(fminf(p0, a3), a2))
#define STEPB_FIRST(P) STEPCORE(P, first0 ? 0.0f : fminf(fminf(p0, a3), a2))

__global__ __launch_bounds__(128, 1) void dtw_dp_kernel(
    const __hip_bfloat16* __restrict__ skew, float* __restrict__ out) {
    __shared__ float4 ring[2][3][8][64];  // 48 KiB: per-wave [bank][row][lane]
    __shared__ float  bnd[2][32][64];     // 16 KiB: [wave][slot][lane]; only [0] read

    const int b   = blockIdx.x;
    const int tid = threadIdx.x;
    const int w   = tid >> 6;
    const int t   = tid & 63;
    const bool lane0  = (t == 0);
    const bool isw1   = (w == 1);
    const bool first0 = (tid == 0);
    const int wbase = w << 11;
    float* bndp = &bnd[0][0][0];

    // this wave's half-row base: batch + w*1024B + t*16B
    const char* Sb = (const char*)skew + (size_t)b * 2654208 + (w << 10) + (t << 4);

    // init bnd to DINF (slots read before first valid write must be inert)
#pragma unroll
    for (int i = 0; i < 32; ++i) bndp[tid + 128 * i] = DINF;
    SBAR();

    float p0 = DINF, p1 = DINF, p2 = DINF, p3 = DINF,
          p4 = DINF, p5 = DINF, p6 = DINF, p7 = DINF;
    float a1 = DINF, a2 = DINF, a3 = DINF;
    float b1 = DINF, b2 = DINF;
    int ro = 18 * 64 + 63;        // slot (0-14)&31 = 18, lane 63
    int wo = wbase | t;           // slot 0

    float4 X, Y;

    // prologue: rows 0-7 -> bank 0, rows 8-15 -> bank 1.
    ISSUE8(0, 0);
    ISSUE8(1, 8);
    VWAIT(8);                     // bank 0 landed (bank 1 in flight)
    DSRD(0, 0, X); DSRD(0, 1, Y);

    // superbody j=0 (steps 0..7)
    ISSUE8(2, 16);
    STEPB_FIRST(X); DSRD(0, 2, X);
    STEPB(Y);       DSRD(0, 3, Y);
    STEPB(X);       DSRD(0, 4, X);
    STEPB(Y);       DSRD(0, 5, Y);
    STEPB(X);       DSRD(0, 6, X);
    STEPB(Y);       DSRD(0, 7, Y);
    VWAIT(8);                     // bank 1 landed (bank 2 in flight)
    STEPB(X);       DSRD(1, 0, X);
    STEPB(Y);       DSRD(1, 1, Y);

    // superbodies j=1..159 (steps 8..1279; last issues rows 1288..1295)
    int rb = 1, nb = 2, ib = 0, base = 24;
#pragma unroll 1
    for (int j = 1; j < 160; ++j) {
        SBAR();                   // lgkm flush only; DMA stays in flight
        ISSUE8(ib, base);
        STEPB(X); DSRD(rb, 2, X);
        STEPB(Y); DSRD(rb, 3, Y);
        STEPB(X); DSRD(rb, 4, X);
        STEPB(Y); DSRD(rb, 5, Y);
        STEPB(X); DSRD(rb, 6, X);
        STEPB(Y); DSRD(rb, 7, Y);
        VWAIT(8);                 // bank nb landed (bank ib in flight)
        STEPB(X); DSRD(nb, 0, X);
        STEPB(Y); DSRD(nb, 1, Y);
        const int orb = rb;
        rb = nb; nb = ib; ib = orb;
        base += 8;
    }

    // superbody j=160 (steps 1280..1287): rb rows 1280-87 landed; no issue.
    SBAR();
    STEPB(X); DSRD(rb, 2, X);
    STEPB(Y); DSRD(rb, 3, Y);
    STEPB(X); DSRD(rb, 4, X);
    STEPB(Y); DSRD(rb, 5, Y);
    STEPB(X); DSRD(rb, 6, X);
    STEPB(Y); DSRD(rb, 7, Y);
    VWAIT(0);                     // bank nb (rows 1288-95) landed
    STEPB(X); DSRD(nb, 0, X);
    STEPB(Y); DSRD(nb, 1, Y);

    // superbody j=161 (steps 1288..1293; k=1293 is the last real cell:
    // lane127 row 1023 -> p7 = dtw[1023][1023]). Padding steps skipped.
    SBAR();
    STEPB(X); DSRD(nb, 2, X);
    STEPB(Y); DSRD(nb, 3, Y);
    STEPB(X); DSRD(nb, 4, X);
    STEPB(Y); DSRD(nb, 5, Y);
    STEPB(X);
    STEPB(Y);

    if (tid == 127) out[b] = 1.0f / (1.0f + p7 * (1.0f / 2048.0f));
}

// ---------------------------------------------------------------------------
extern "C" void kernel_launch(void* const* d_in, const int* in_sizes, int n_in,
                              void* d_out, int out_size, void* d_ws, size_t ws_size,
                              hipStream_t stream) {
    const float* s1 = (const float*)d_in[0];
    const float* s2 = (const float*)d_in[1];
    float* out = (float*)d_out;

    char* ws = (char*)d_ws;
    __hip_bfloat16* Abf  = (__hip_bfloat16*)(ws);                // 25165824 B
    __hip_bfloat16* Bbf  = (__hip_bfloat16*)(ws + 25165824);     // 25165824 B
    __hip_bfloat16* skew = (__hip_bfloat16*)(ws + 50331648);     // 16*1296*1024*2 = 42467328 B

    // zero skew: parallelogram holes must be 0 (absorbed by the DINF flow)
    hipMemsetAsync(skew, 0, (size_t)16 * 1296 * 1024 * 2, stream);

    norm_bf16_kernel<<<8192, 256, 0, stream>>>(s1, s2, Abf, Bbf);
    gemm_dist_kernel<<<16 * 64, 256, 0, stream>>>(Abf, Bbf, skew);
    dtw_dp_kernel<<<16, 128, 0, stream>>>(skew, out);
}